// Round 5
// baseline (444.905 us; speedup 1.0000x reference)
//
#include <hip/hip_runtime.h>
#include <hip/hip_bf16.h>
#include <hip/hip_fp16.h>

// GraphSAGE(2-layer, mean agg) + 3-layer MLP link predictor.
// N=100000, E=1.6M, E_PAIR=100000, D=128.
// Round 5: k_mlp gather-once + double-buffered weight staging (1 barrier/chunk);
// k_transform double-buffered; k_agg 4-deep unroll; vectorized edge reads.

#define D 128
#define SCAN_B 512
#define LDA 40       // f16 elems per staged row (80B stride: 2-way banks = free)
#define LDC 264      // s_cat row stride f16 (528B: 2-way banks = free)

typedef _Float16 f16x8 __attribute__((ext_vector_type(8)));
typedef float f32x4 __attribute__((ext_vector_type(4)));

// ---------------- CSR build ----------------
__global__ void k_count_deg(const int* __restrict__ dst, int* __restrict__ cnt, int e) {
    int i = (blockIdx.x * 256 + threadIdx.x) * 4;
    if (i + 4 <= e) {
        int4 d = *(const int4*)(dst + i);
        atomicAdd(&cnt[d.x], 1);
        atomicAdd(&cnt[d.y], 1);
        atomicAdd(&cnt[d.z], 1);
        atomicAdd(&cnt[d.w], 1);
    } else {
        for (; i < e; ++i) atomicAdd(&cnt[dst[i]], 1);
    }
}

__global__ void k_scan_block(const int* __restrict__ deg, int* __restrict__ row_off,
                             int* __restrict__ bsums, int n) {
    __shared__ int s[SCAN_B];
    int i = blockIdx.x * SCAN_B + threadIdx.x;
    int v = (i < n) ? deg[i] : 0;
    s[threadIdx.x] = v;
    __syncthreads();
    for (int off = 1; off < SCAN_B; off <<= 1) {
        int add = (threadIdx.x >= off) ? s[threadIdx.x - off] : 0;
        __syncthreads();
        s[threadIdx.x] += add;
        __syncthreads();
    }
    if (i < n) row_off[i + 1] = s[threadIdx.x];
    if (threadIdx.x == SCAN_B - 1) bsums[blockIdx.x] = s[threadIdx.x];
}

__global__ void k_scan_sums(int* __restrict__ bsums, int nb) {
    if (blockIdx.x == 0 && threadIdx.x == 0) {
        int run = 0;
        for (int b = 0; b < nb; ++b) { int t = bsums[b]; bsums[b] = run; run += t; }
    }
}

__global__ void k_scan_add(int* __restrict__ row_off, const int* __restrict__ bsums, int n) {
    int i = blockIdx.x * SCAN_B + threadIdx.x;
    if (i < n) row_off[i + 1] += bsums[blockIdx.x];
    if (i == 0) row_off[0] = 0;
}

__global__ void k_scatter(const int* __restrict__ src, const int* __restrict__ dst,
                          const int* __restrict__ row_off, int* __restrict__ cursor,
                          int* __restrict__ csr, int e) {
    int i = (blockIdx.x * 256 + threadIdx.x) * 4;
    if (i + 4 <= e) {
        int4 s = *(const int4*)(src + i);
        int4 d = *(const int4*)(dst + i);
        int p;
        p = atomicAdd(&cursor[d.x], 1); __builtin_nontemporal_store(s.x, &csr[row_off[d.x] + p]);
        p = atomicAdd(&cursor[d.y], 1); __builtin_nontemporal_store(s.y, &csr[row_off[d.y] + p]);
        p = atomicAdd(&cursor[d.z], 1); __builtin_nontemporal_store(s.z, &csr[row_off[d.z] + p]);
        p = atomicAdd(&cursor[d.w], 1); __builtin_nontemporal_store(s.w, &csr[row_off[d.w] + p]);
    } else {
        for (; i < e; ++i) {
            int dd = dst[i];
            int p = atomicAdd(&cursor[dd], 1);
            __builtin_nontemporal_store(src[i], &csr[row_off[dd] + p]);
        }
    }
}

// ---------------- f32 -> f16 convert ----------------
__global__ void k_cvt_f16(const float* __restrict__ src, _Float16* __restrict__ dst, int n8) {
    int i = blockIdx.x * 256 + threadIdx.x;
    if (i >= n8) return;
    const float4* s4 = (const float4*)src;
    float4 a = s4[2 * i], b = s4[2 * i + 1];
    f16x8 h;
    h[0] = (_Float16)a.x; h[1] = (_Float16)a.y; h[2] = (_Float16)a.z; h[3] = (_Float16)a.w;
    h[4] = (_Float16)b.x; h[5] = (_Float16)b.y; h[6] = (_Float16)b.z; h[7] = (_Float16)b.w;
    *(f16x8*)(dst + 8 * i) = h;
}

// ---------------- mean aggregation: 16-lane group per node, 4-deep ----------------
__global__ __launch_bounds__(256) void k_agg(
    const _Float16* __restrict__ Xf, const int* __restrict__ row_off,
    const int* __restrict__ csr, _Float16* __restrict__ Aggf, int n_nodes) {
    int g = blockIdx.x * 16 + (threadIdx.x >> 4);
    if (g >= n_nodes) return;
    int l = threadIdx.x & 15;
    int beg = row_off[g], end = row_off[g + 1];
    float acc[8] = {0.f, 0.f, 0.f, 0.f, 0.f, 0.f, 0.f, 0.f};
    int i = beg;
    for (; i + 4 <= end; i += 4) {
        int s0 = csr[i], s1 = csr[i + 1], s2 = csr[i + 2], s3 = csr[i + 3];
        f16x8 v0 = *(const f16x8*)(Xf + (size_t)s0 * D + l * 8);
        f16x8 v1 = *(const f16x8*)(Xf + (size_t)s1 * D + l * 8);
        f16x8 v2 = *(const f16x8*)(Xf + (size_t)s2 * D + l * 8);
        f16x8 v3 = *(const f16x8*)(Xf + (size_t)s3 * D + l * 8);
        #pragma unroll
        for (int j = 0; j < 8; ++j)
            acc[j] += ((float)v0[j] + (float)v1[j]) + ((float)v2[j] + (float)v3[j]);
    }
    for (; i < end; ++i) {
        int s0 = csr[i];
        f16x8 v0 = *(const f16x8*)(Xf + (size_t)s0 * D + l * 8);
        #pragma unroll
        for (int j = 0; j < 8; ++j) acc[j] += (float)v0[j];
    }
    float inv = 1.0f / fmaxf((float)(end - beg), 1.0f);
    f16x8 o;
    #pragma unroll
    for (int j = 0; j < 8; ++j) o[j] = (_Float16)(acc[j] * inv);
    *(f16x8*)(Aggf + (size_t)g * D + l * 8) = o;
}

// ---------------- layer transform (MFMA, double-buffered) ----------------
// 512 thr = 8 waves; tile 128x128; wave (wr=w>>1, wc=w&1): rows [32wr,+32), cols [64wc,+64).
__global__ __launch_bounds__(512) void k_transform(
    const _Float16* __restrict__ Xf, const _Float16* __restrict__ Aggf,
    const _Float16* __restrict__ Wsf, const _Float16* __restrict__ Wnf,
    const float* __restrict__ bias, _Float16* __restrict__ outf,
    int n_rows, int do_relu) {
    __shared__ _Float16 s_a[2][128 * LDA];
    __shared__ _Float16 s_b[2][128 * LDA];
    int tid = threadIdx.x;
    int w = tid >> 6, l = tid & 63;
    int wr = w >> 1, wc = w & 1;
    int l15 = l & 15, lk = l >> 4;
    int n0 = blockIdx.x * 128;
    int r = tid >> 2, q = tid & 3;
    int rstage = n0 + r; if (rstage >= n_rows) rstage = n_rows - 1;

    f32x4 acc[2][4];
    #pragma unroll
    for (int i = 0; i < 2; ++i)
        #pragma unroll
        for (int j = 0; j < 4; ++j) acc[i][j] = (f32x4){0.f, 0.f, 0.f, 0.f};

    int a_off = (wr * 32 + l15) * LDA + lk * 8;
    int b_off = (wc * 64 + l15) * LDA + lk * 8;
    int st_off = r * LDA + q * 8;

    // prologue: stage chunk 0
    {
        f16x8 av = *(const f16x8*)(Xf + (size_t)rstage * D + q * 8);
        f16x8 wv = *(const f16x8*)(Wsf + (size_t)r * D + q * 8);
        *(f16x8*)(&s_a[0][st_off]) = av;
        *(f16x8*)(&s_b[0][st_off]) = wv;
    }
    __syncthreads();

    for (int c = 0; c < 8; ++c) {
        int b = c & 1;
        f16x8 av, wv;
        if (c < 7) {
            int cn = c + 1;
            const _Float16* asrc = (cn < 4) ? Xf : Aggf;
            const _Float16* wsrc = (cn < 4) ? Wsf : Wnf;
            int kb = (cn & 3) * 32;
            av = *(const f16x8*)(asrc + (size_t)rstage * D + kb + q * 8);
            wv = *(const f16x8*)(wsrc + (size_t)r * D + kb + q * 8);
        }
        f16x8 af[2], bf[4];
        af[0] = *(const f16x8*)(&s_a[b][a_off]);
        af[1] = *(const f16x8*)(&s_a[b][a_off + 16 * LDA]);
        #pragma unroll
        for (int j = 0; j < 4; ++j) bf[j] = *(const f16x8*)(&s_b[b][b_off + j * 16 * LDA]);
        #pragma unroll
        for (int i = 0; i < 2; ++i)
            #pragma unroll
            for (int j = 0; j < 4; ++j)
                acc[i][j] = __builtin_amdgcn_mfma_f32_16x16x32_f16(af[i], bf[j], acc[i][j], 0, 0, 0);
        if (c < 7) {
            *(f16x8*)(&s_a[b ^ 1][st_off]) = av;
            *(f16x8*)(&s_b[b ^ 1][st_off]) = wv;
        }
        __syncthreads();
    }

    #pragma unroll
    for (int j = 0; j < 4; ++j) {
        int col = wc * 64 + j * 16 + l15;
        float bv = bias[col];
        #pragma unroll
        for (int i = 0; i < 2; ++i) {
            int rowb = n0 + wr * 32 + i * 16 + lk * 4;
            #pragma unroll
            for (int v = 0; v < 4; ++v) {
                int row = rowb + v;
                if (row < n_rows) {
                    float xv = acc[i][j][v] + bv;
                    if (do_relu) xv = fmaxf(xv, 0.f);
                    outf[(size_t)row * D + col] = (_Float16)xv;
                }
            }
        }
    }
}

// ---------------- fused predictor: gather-once, dbl-buffered weights ----------------
// 256 thr = 4 waves; 64 pairs/block; tile 64x128; wave (wr,wc): rows [32wr,+32), cols [64wc,+64).
__global__ __launch_bounds__(256) void k_mlp(
    const _Float16* __restrict__ Hf,
    const int* __restrict__ pos_src, const int* __restrict__ pos_dst,
    const int* __restrict__ neg_src, const int* __restrict__ neg_dst,
    const _Float16* __restrict__ P1wf, const float* __restrict__ P1b,
    const _Float16* __restrict__ P2wf, const float* __restrict__ P2b,
    const float* __restrict__ P3w, const float* __restrict__ P3b,
    float* __restrict__ out, int EP) {
    __shared__ _Float16 s_cat[64 * LDC];      // cat tile [64 pairs][256]; later h1 in cols 0..127
    __shared__ _Float16 s_b[2][128 * LDA];    // weight chunk double buffer
    __shared__ float s_red[64 * 2];
    __shared__ int s_node[128];               // [0..63] src, [64..127] dst
    int tid = threadIdx.x;
    int w = tid >> 6, l = tid & 63;
    int wr = w >> 1, wc = w & 1;
    int l15 = l & 15, lk = l >> 4;
    int p0 = blockIdx.x * 64;
    int twoEP = 2 * EP;

    if (tid < 128) {
        int p = p0 + (tid & 63);
        if (p >= twoEP) p = twoEP - 1;
        int node;
        if (tid < 64) node = (p < EP) ? pos_src[p] : neg_src[p - EP];
        else          node = (p < EP) ? pos_dst[p] : neg_dst[p - EP];
        s_node[tid] = node;
    }
    __syncthreads();

    // gather full cat tile: 128 node-rows x 16 f16x8 units
    #pragma unroll
    for (int e = 0; e < 8; ++e) {
        int idx = tid + e * 256;
        int rr = idx >> 4, u = idx & 15;
        int node = s_node[rr];
        f16x8 v = *(const f16x8*)(Hf + (size_t)node * D + u * 8);
        *(f16x8*)(s_cat + (rr & 63) * LDC + (rr >> 6) * 128 + u * 8) = v;
    }
    // stage W1 chunk 0
    #pragma unroll
    for (int e = 0; e < 2; ++e) {
        int idx = tid + e * 256;
        int o = idx >> 2, q = idx & 3;
        *(f16x8*)(&s_b[0][o * LDA + q * 8]) = *(const f16x8*)(P1wf + (size_t)o * 256 + q * 8);
    }
    __syncthreads();

    f32x4 acc[2][4];
    #pragma unroll
    for (int i = 0; i < 2; ++i)
        #pragma unroll
        for (int j = 0; j < 4; ++j) acc[i][j] = (f32x4){0.f, 0.f, 0.f, 0.f};

    // ---- P1: [64 x 256] @ W1^T, 8 chunks, 1 barrier each ----
    for (int c = 0; c < 8; ++c) {
        int b = c & 1;
        f16x8 nw[2];
        if (c < 7) {
            #pragma unroll
            for (int e = 0; e < 2; ++e) {
                int idx = tid + e * 256;
                int o = idx >> 2, q = idx & 3;
                nw[e] = *(const f16x8*)(P1wf + (size_t)o * 256 + (c + 1) * 32 + q * 8);
            }
        }
        f16x8 af[2], bf[4];
        af[0] = *(const f16x8*)(s_cat + (wr * 32 + l15) * LDC + c * 32 + lk * 8);
        af[1] = *(const f16x8*)(s_cat + (wr * 32 + 16 + l15) * LDC + c * 32 + lk * 8);
        #pragma unroll
        for (int j = 0; j < 4; ++j)
            bf[j] = *(const f16x8*)(&s_b[b][(wc * 64 + j * 16 + l15) * LDA + lk * 8]);
        #pragma unroll
        for (int i = 0; i < 2; ++i)
            #pragma unroll
            for (int j = 0; j < 4; ++j)
                acc[i][j] = __builtin_amdgcn_mfma_f32_16x16x32_f16(af[i], bf[j], acc[i][j], 0, 0, 0);
        if (c < 7) {
            #pragma unroll
            for (int e = 0; e < 2; ++e) {
                int idx = tid + e * 256;
                int o = idx >> 2, q = idx & 3;
                *(f16x8*)(&s_b[b ^ 1][o * LDA + q * 8]) = nw[e];
            }
        }
        __syncthreads();
    }

    // h1 = relu(acc + P1b) -> s_cat cols 0..127 ; stage W2 chunk 0
    #pragma unroll
    for (int j = 0; j < 4; ++j) {
        int col = wc * 64 + j * 16 + l15;
        float bv = P1b[col];
        #pragma unroll
        for (int i = 0; i < 2; ++i) {
            int rowb = wr * 32 + i * 16 + lk * 4;
            #pragma unroll
            for (int v = 0; v < 4; ++v)
                s_cat[(rowb + v) * LDC + col] = (_Float16)fmaxf(acc[i][j][v] + bv, 0.f);
        }
    }
    #pragma unroll
    for (int e = 0; e < 2; ++e) {
        int idx = tid + e * 256;
        int o = idx >> 2, q = idx & 3;
        *(f16x8*)(&s_b[0][o * LDA + q * 8]) = *(const f16x8*)(P2wf + (size_t)o * D + q * 8);
    }
    __syncthreads();

    // ---- P2: [64 x 128] @ W2^T, 4 chunks ----
    f32x4 acc2[2][4];
    #pragma unroll
    for (int i = 0; i < 2; ++i)
        #pragma unroll
        for (int j = 0; j < 4; ++j) acc2[i][j] = (f32x4){0.f, 0.f, 0.f, 0.f};

    for (int c = 0; c < 4; ++c) {
        int b = c & 1;
        f16x8 nw[2];
        if (c < 3) {
            #pragma unroll
            for (int e = 0; e < 2; ++e) {
                int idx = tid + e * 256;
                int o = idx >> 2, q = idx & 3;
                nw[e] = *(const f16x8*)(P2wf + (size_t)o * D + (c + 1) * 32 + q * 8);
            }
        }
        f16x8 af[2], bf[4];
        af[0] = *(const f16x8*)(s_cat + (wr * 32 + l15) * LDC + c * 32 + lk * 8);
        af[1] = *(const f16x8*)(s_cat + (wr * 32 + 16 + l15) * LDC + c * 32 + lk * 8);
        #pragma unroll
        for (int j = 0; j < 4; ++j)
            bf[j] = *(const f16x8*)(&s_b[b][(wc * 64 + j * 16 + l15) * LDA + lk * 8]);
        #pragma unroll
        for (int i = 0; i < 2; ++i)
            #pragma unroll
            for (int j = 0; j < 4; ++j)
                acc2[i][j] = __builtin_amdgcn_mfma_f32_16x16x32_f16(af[i], bf[j], acc2[i][j], 0, 0, 0);
        if (c < 3) {
            #pragma unroll
            for (int e = 0; e < 2; ++e) {
                int idx = tid + e * 256;
                int o = idx >> 2, q = idx & 3;
                *(f16x8*)(&s_b[b ^ 1][o * LDA + q * 8]) = nw[e];
            }
        }
        __syncthreads();
    }

    // ---- P3 ----
    float b2v[4], pw[4];
    #pragma unroll
    for (int j = 0; j < 4; ++j) {
        int col = wc * 64 + j * 16 + l15;
        b2v[j] = P2b[col];
        pw[j] = P3w[col];
    }
    #pragma unroll
    for (int i = 0; i < 2; ++i) {
        #pragma unroll
        for (int v = 0; v < 4; ++v) {
            float s = 0.f;
            #pragma unroll
            for (int j = 0; j < 4; ++j)
                s += fmaxf(acc2[i][j][v] + b2v[j], 0.f) * pw[j];
            s += __shfl_xor(s, 1);
            s += __shfl_xor(s, 2);
            s += __shfl_xor(s, 4);
            s += __shfl_xor(s, 8);
            if (l15 == 0)
                s_red[(wr * 32 + i * 16 + lk * 4 + v) * 2 + wc] = s;
        }
    }
    __syncthreads();
    if (tid < 64) {
        int p = p0 + tid;
        if (p < twoEP) out[p] = s_red[tid * 2] + s_red[tid * 2 + 1] + P3b[0];
    }
}

static inline size_t align_up(size_t x, size_t a) { return (x + a - 1) & ~(a - 1); }

extern "C" void kernel_launch(void* const* d_in, const int* in_sizes, int n_in,
                              void* d_out, int out_size, void* d_ws, size_t ws_size,
                              hipStream_t stream) {
    const float* x        = (const float*)d_in[0];
    const int*   edge_src = (const int*)d_in[1];
    const int*   edge_dst = (const int*)d_in[2];
    const int*   pos_src  = (const int*)d_in[3];
    const int*   pos_dst  = (const int*)d_in[4];
    const int*   neg_src  = (const int*)d_in[5];
    const int*   neg_dst  = (const int*)d_in[6];
    const float* W1n = (const float*)d_in[7];
    const float* W1s = (const float*)d_in[8];
    const float* b1  = (const float*)d_in[9];
    const float* W2n = (const float*)d_in[10];
    const float* W2s = (const float*)d_in[11];
    const float* b2  = (const float*)d_in[12];
    const float* P1w = (const float*)d_in[13];
    const float* P1b = (const float*)d_in[14];
    const float* P2w = (const float*)d_in[15];
    const float* P2b = (const float*)d_in[16];
    const float* P3w = (const float*)d_in[17];
    const float* P3b = (const float*)d_in[18];
    float* out = (float*)d_out;

    const int N = in_sizes[0] / D;
    const int E = in_sizes[1];
    const int EP = in_sizes[3];

    char* ws = (char*)d_ws;
    size_t off = 0;
    int* row_off = (int*)(ws + off); off = align_up(off + (size_t)(N + 1) * 4, 256);
    int* cursor  = (int*)(ws + off); off = align_up(off + (size_t)N * 4, 256);
    int* bsums   = (int*)(ws + off); off = align_up(off + 4096, 256);
    int* csr     = (int*)(ws + off); off = align_up(off + (size_t)E * 4, 256);
    _Float16* xf   = (_Float16*)(ws + off); off = align_up(off + (size_t)N * D * 2, 256);
    _Float16* aggf = (_Float16*)(ws + off); off = align_up(off + (size_t)N * D * 2, 256);
    _Float16* h1f  = (_Float16*)(ws + off); off = align_up(off + (size_t)N * D * 2, 256);
    _Float16* h2f  = (_Float16*)(ws + off); off = align_up(off + (size_t)N * D * 2, 256);
    _Float16* Ws1f = (_Float16*)(ws + off); off = align_up(off + (size_t)D * D * 2, 256);
    _Float16* Wn1f = (_Float16*)(ws + off); off = align_up(off + (size_t)D * D * 2, 256);
    _Float16* Ws2f = (_Float16*)(ws + off); off = align_up(off + (size_t)D * D * 2, 256);
    _Float16* Wn2f = (_Float16*)(ws + off); off = align_up(off + (size_t)D * D * 2, 256);
    _Float16* P1wf = (_Float16*)(ws + off); off = align_up(off + (size_t)2 * D * D * 2, 256);
    _Float16* P2wf = (_Float16*)(ws + off); off = align_up(off + (size_t)D * D * 2, 256);
    (void)ws_size;

    const int nb_scan = (N + SCAN_B - 1) / SCAN_B;

    // --- CSR build ---
    hipMemsetAsync(cursor, 0, (size_t)N * 4, stream);
    k_count_deg<<<(E / 4 + 255) / 256, 256, 0, stream>>>(edge_dst, cursor, E);
    k_scan_block<<<nb_scan, SCAN_B, 0, stream>>>(cursor, row_off, bsums, N);
    k_scan_sums<<<1, 64, 0, stream>>>(bsums, nb_scan);
    k_scan_add<<<nb_scan, SCAN_B, 0, stream>>>(row_off, bsums, N);
    hipMemsetAsync(cursor, 0, (size_t)N * 4, stream);
    k_scatter<<<(E / 4 + 255) / 256, 256, 0, stream>>>(edge_src, edge_dst, row_off, cursor, csr, E);

    // --- f16 conversions ---
    k_cvt_f16<<<(N * D / 8 + 255) / 256, 256, 0, stream>>>(x, xf, N * D / 8);
    k_cvt_f16<<<(D * D / 8 + 255) / 256, 256, 0, stream>>>(W1s, Ws1f, D * D / 8);
    k_cvt_f16<<<(D * D / 8 + 255) / 256, 256, 0, stream>>>(W1n, Wn1f, D * D / 8);
    k_cvt_f16<<<(D * D / 8 + 255) / 256, 256, 0, stream>>>(W2s, Ws2f, D * D / 8);
    k_cvt_f16<<<(D * D / 8 + 255) / 256, 256, 0, stream>>>(W2n, Wn2f, D * D / 8);
    k_cvt_f16<<<(2 * D * D / 8 + 255) / 256, 256, 0, stream>>>(P1w, P1wf, 2 * D * D / 8);
    k_cvt_f16<<<(D * D / 8 + 255) / 256, 256, 0, stream>>>(P2w, P2wf, D * D / 8);

    const int ngrid = (N + 127) / 128;
    const int pgrid = (2 * EP + 63) / 64;

    // --- layer 1 ---
    k_agg<<<(N + 15) / 16, 256, 0, stream>>>(xf, row_off, csr, aggf, N);
    k_transform<<<ngrid, 512, 0, stream>>>(xf, aggf, Ws1f, Wn1f, b1, h1f, N, 1);
    // --- layer 2 ---
    k_agg<<<(N + 15) / 16, 256, 0, stream>>>(h1f, row_off, csr, aggf, N);
    k_transform<<<ngrid, 512, 0, stream>>>(h1f, aggf, Ws2f, Wn2f, b2, h2f, N, 0);

    // --- fused predictor ---
    k_mlp<<<pgrid, 256, 0, stream>>>(h2f, pos_src, pos_dst, neg_src, neg_dst,
                                     P1wf, P1b, P2wf, P2b, P3w, P3b, out, EP);
}

// Round 6
// 426.942 us; speedup vs baseline: 1.0421x; 1.0421x over previous
//
#include <hip/hip_runtime.h>
#include <hip/hip_bf16.h>
#include <hip/hip_fp16.h>

// GraphSAGE(2-layer, mean agg) + 3-layer MLP link predictor.
// N=100000, E=1.6M, E_PAIR=100000, D=128.
// Round 6: XCD-region-partitioned CSR build (count+scatter filter by dst region,
// region = blockIdx&7) -> csr/cursor/cnt lines stay in one XCD's L2, write-once.

#define D 128
#define SCAN_B 512
#define LDA 40       // f16 elems per staged row (80B stride: 2-way banks = free)
#define LDC 264      // s_cat row stride f16 (528B: 2-way banks = free)

typedef _Float16 f16x8 __attribute__((ext_vector_type(8)));
typedef float f32x4 __attribute__((ext_vector_type(4)));

// ---------------- CSR build (XCD-region partitioned) ----------------
// block b: region = b&7 (maps to one XCD under round-robin dispatch),
// slice = b>>3 of the edge list. Only edges with dst in the region are handled,
// so cnt/cursor/csr lines for a region are touched by a single XCD.
__global__ __launch_bounds__(256) void k_count_deg(
    const int* __restrict__ dst, int* __restrict__ cnt, int e, int n) {
    int region = blockIdx.x & 7;
    int slice = blockIdx.x >> 3;
    int nslice = gridDim.x >> 3;
    int e4 = e >> 2;
    int per = (e4 + nslice - 1) / nslice;
    int beg4 = slice * per;
    int end4 = min(beg4 + per, e4);
    int bound = (n + 7) / 8;
    int rlo = region * bound, rhi = rlo + bound;
    for (int i4 = beg4 + threadIdx.x; i4 < end4; i4 += 256) {
        int4 d = ((const int4*)dst)[i4];
        if (d.x >= rlo && d.x < rhi) atomicAdd(&cnt[d.x], 1);
        if (d.y >= rlo && d.y < rhi) atomicAdd(&cnt[d.y], 1);
        if (d.z >= rlo && d.z < rhi) atomicAdd(&cnt[d.z], 1);
        if (d.w >= rlo && d.w < rhi) atomicAdd(&cnt[d.w], 1);
    }
    if (slice == nslice - 1) {
        for (int i = e4 * 4 + threadIdx.x; i < e; i += 256) {
            int d = dst[i];
            if (d >= rlo && d < rhi) atomicAdd(&cnt[d], 1);
        }
    }
}

__global__ void k_scan_block(const int* __restrict__ deg, int* __restrict__ row_off,
                             int* __restrict__ bsums, int n) {
    __shared__ int s[SCAN_B];
    int i = blockIdx.x * SCAN_B + threadIdx.x;
    int v = (i < n) ? deg[i] : 0;
    s[threadIdx.x] = v;
    __syncthreads();
    for (int off = 1; off < SCAN_B; off <<= 1) {
        int add = (threadIdx.x >= off) ? s[threadIdx.x - off] : 0;
        __syncthreads();
        s[threadIdx.x] += add;
        __syncthreads();
    }
    if (i < n) row_off[i + 1] = s[threadIdx.x];
    if (threadIdx.x == SCAN_B - 1) bsums[blockIdx.x] = s[threadIdx.x];
}

__global__ void k_scan_sums(int* __restrict__ bsums, int nb) {
    if (blockIdx.x == 0 && threadIdx.x == 0) {
        int run = 0;
        for (int b = 0; b < nb; ++b) { int t = bsums[b]; bsums[b] = run; run += t; }
    }
}

__global__ void k_scan_add(int* __restrict__ row_off, const int* __restrict__ bsums, int n) {
    int i = blockIdx.x * SCAN_B + threadIdx.x;
    if (i < n) row_off[i + 1] += bsums[blockIdx.x];
    if (i == 0) row_off[0] = 0;
}

__global__ __launch_bounds__(256) void k_scatter(
    const int* __restrict__ src, const int* __restrict__ dst,
    const int* __restrict__ row_off, int* __restrict__ cursor,
    int* __restrict__ csr, int e, int n) {
    int region = blockIdx.x & 7;
    int slice = blockIdx.x >> 3;
    int nslice = gridDim.x >> 3;
    int e4 = e >> 2;
    int per = (e4 + nslice - 1) / nslice;
    int beg4 = slice * per;
    int end4 = min(beg4 + per, e4);
    int bound = (n + 7) / 8;
    int rlo = region * bound, rhi = rlo + bound;
    for (int i4 = beg4 + threadIdx.x; i4 < end4; i4 += 256) {
        int4 d = ((const int4*)dst)[i4];
        int4 s = ((const int4*)src)[i4];
        if (d.x >= rlo && d.x < rhi) { int p = atomicAdd(&cursor[d.x], 1); csr[row_off[d.x] + p] = s.x; }
        if (d.y >= rlo && d.y < rhi) { int p = atomicAdd(&cursor[d.y], 1); csr[row_off[d.y] + p] = s.y; }
        if (d.z >= rlo && d.z < rhi) { int p = atomicAdd(&cursor[d.z], 1); csr[row_off[d.z] + p] = s.z; }
        if (d.w >= rlo && d.w < rhi) { int p = atomicAdd(&cursor[d.w], 1); csr[row_off[d.w] + p] = s.w; }
    }
    if (slice == nslice - 1) {
        for (int i = e4 * 4 + threadIdx.x; i < e; i += 256) {
            int d = dst[i];
            if (d >= rlo && d < rhi) {
                int p = atomicAdd(&cursor[d], 1);
                csr[row_off[d] + p] = src[i];
            }
        }
    }
}

// ---------------- f32 -> f16 convert ----------------
__global__ void k_cvt_f16(const float* __restrict__ src, _Float16* __restrict__ dst, int n8) {
    int i = blockIdx.x * 256 + threadIdx.x;
    if (i >= n8) return;
    const float4* s4 = (const float4*)src;
    float4 a = s4[2 * i], b = s4[2 * i + 1];
    f16x8 h;
    h[0] = (_Float16)a.x; h[1] = (_Float16)a.y; h[2] = (_Float16)a.z; h[3] = (_Float16)a.w;
    h[4] = (_Float16)b.x; h[5] = (_Float16)b.y; h[6] = (_Float16)b.z; h[7] = (_Float16)b.w;
    *(f16x8*)(dst + 8 * i) = h;
}

// ---------------- mean aggregation: 16-lane group per node, 4-deep ----------------
__global__ __launch_bounds__(256) void k_agg(
    const _Float16* __restrict__ Xf, const int* __restrict__ row_off,
    const int* __restrict__ csr, _Float16* __restrict__ Aggf, int n_nodes) {
    int g = blockIdx.x * 16 + (threadIdx.x >> 4);
    if (g >= n_nodes) return;
    int l = threadIdx.x & 15;
    int beg = row_off[g], end = row_off[g + 1];
    float acc[8] = {0.f, 0.f, 0.f, 0.f, 0.f, 0.f, 0.f, 0.f};
    int i = beg;
    for (; i + 4 <= end; i += 4) {
        int s0 = csr[i], s1 = csr[i + 1], s2 = csr[i + 2], s3 = csr[i + 3];
        f16x8 v0 = *(const f16x8*)(Xf + (size_t)s0 * D + l * 8);
        f16x8 v1 = *(const f16x8*)(Xf + (size_t)s1 * D + l * 8);
        f16x8 v2 = *(const f16x8*)(Xf + (size_t)s2 * D + l * 8);
        f16x8 v3 = *(const f16x8*)(Xf + (size_t)s3 * D + l * 8);
        #pragma unroll
        for (int j = 0; j < 8; ++j)
            acc[j] += ((float)v0[j] + (float)v1[j]) + ((float)v2[j] + (float)v3[j]);
    }
    for (; i < end; ++i) {
        int s0 = csr[i];
        f16x8 v0 = *(const f16x8*)(Xf + (size_t)s0 * D + l * 8);
        #pragma unroll
        for (int j = 0; j < 8; ++j) acc[j] += (float)v0[j];
    }
    float inv = 1.0f / fmaxf((float)(end - beg), 1.0f);
    f16x8 o;
    #pragma unroll
    for (int j = 0; j < 8; ++j) o[j] = (_Float16)(acc[j] * inv);
    *(f16x8*)(Aggf + (size_t)g * D + l * 8) = o;
}

// ---------------- layer transform (MFMA, double-buffered) ----------------
// 512 thr = 8 waves; tile 128x128; wave (wr=w>>1, wc=w&1): rows [32wr,+32), cols [64wc,+64).
__global__ __launch_bounds__(512) void k_transform(
    const _Float16* __restrict__ Xf, const _Float16* __restrict__ Aggf,
    const _Float16* __restrict__ Wsf, const _Float16* __restrict__ Wnf,
    const float* __restrict__ bias, _Float16* __restrict__ outf,
    int n_rows, int do_relu) {
    __shared__ _Float16 s_a[2][128 * LDA];
    __shared__ _Float16 s_b[2][128 * LDA];
    int tid = threadIdx.x;
    int w = tid >> 6, l = tid & 63;
    int wr = w >> 1, wc = w & 1;
    int l15 = l & 15, lk = l >> 4;
    int n0 = blockIdx.x * 128;
    int r = tid >> 2, q = tid & 3;
    int rstage = n0 + r; if (rstage >= n_rows) rstage = n_rows - 1;

    f32x4 acc[2][4];
    #pragma unroll
    for (int i = 0; i < 2; ++i)
        #pragma unroll
        for (int j = 0; j < 4; ++j) acc[i][j] = (f32x4){0.f, 0.f, 0.f, 0.f};

    int a_off = (wr * 32 + l15) * LDA + lk * 8;
    int b_off = (wc * 64 + l15) * LDA + lk * 8;
    int st_off = r * LDA + q * 8;

    {
        f16x8 av = *(const f16x8*)(Xf + (size_t)rstage * D + q * 8);
        f16x8 wv = *(const f16x8*)(Wsf + (size_t)r * D + q * 8);
        *(f16x8*)(&s_a[0][st_off]) = av;
        *(f16x8*)(&s_b[0][st_off]) = wv;
    }
    __syncthreads();

    for (int c = 0; c < 8; ++c) {
        int b = c & 1;
        f16x8 av, wv;
        if (c < 7) {
            int cn = c + 1;
            const _Float16* asrc = (cn < 4) ? Xf : Aggf;
            const _Float16* wsrc = (cn < 4) ? Wsf : Wnf;
            int kb = (cn & 3) * 32;
            av = *(const f16x8*)(asrc + (size_t)rstage * D + kb + q * 8);
            wv = *(const f16x8*)(wsrc + (size_t)r * D + kb + q * 8);
        }
        f16x8 af[2], bf[4];
        af[0] = *(const f16x8*)(&s_a[b][a_off]);
        af[1] = *(const f16x8*)(&s_a[b][a_off + 16 * LDA]);
        #pragma unroll
        for (int j = 0; j < 4; ++j) bf[j] = *(const f16x8*)(&s_b[b][b_off + j * 16 * LDA]);
        #pragma unroll
        for (int i = 0; i < 2; ++i)
            #pragma unroll
            for (int j = 0; j < 4; ++j)
                acc[i][j] = __builtin_amdgcn_mfma_f32_16x16x32_f16(af[i], bf[j], acc[i][j], 0, 0, 0);
        if (c < 7) {
            *(f16x8*)(&s_a[b ^ 1][st_off]) = av;
            *(f16x8*)(&s_b[b ^ 1][st_off]) = wv;
        }
        __syncthreads();
    }

    #pragma unroll
    for (int j = 0; j < 4; ++j) {
        int col = wc * 64 + j * 16 + l15;
        float bv = bias[col];
        #pragma unroll
        for (int i = 0; i < 2; ++i) {
            int rowb = n0 + wr * 32 + i * 16 + lk * 4;
            #pragma unroll
            for (int v = 0; v < 4; ++v) {
                int row = rowb + v;
                if (row < n_rows) {
                    float xv = acc[i][j][v] + bv;
                    if (do_relu) xv = fmaxf(xv, 0.f);
                    outf[(size_t)row * D + col] = (_Float16)xv;
                }
            }
        }
    }
}

// ---------------- fused predictor: gather-once, dbl-buffered weights ----------------
__global__ __launch_bounds__(256) void k_mlp(
    const _Float16* __restrict__ Hf,
    const int* __restrict__ pos_src, const int* __restrict__ pos_dst,
    const int* __restrict__ neg_src, const int* __restrict__ neg_dst,
    const _Float16* __restrict__ P1wf, const float* __restrict__ P1b,
    const _Float16* __restrict__ P2wf, const float* __restrict__ P2b,
    const float* __restrict__ P3w, const float* __restrict__ P3b,
    float* __restrict__ out, int EP) {
    __shared__ _Float16 s_cat[64 * LDC];
    __shared__ _Float16 s_b[2][128 * LDA];
    __shared__ float s_red[64 * 2];
    __shared__ int s_node[128];
    int tid = threadIdx.x;
    int w = tid >> 6, l = tid & 63;
    int wr = w >> 1, wc = w & 1;
    int l15 = l & 15, lk = l >> 4;
    int p0 = blockIdx.x * 64;
    int twoEP = 2 * EP;

    if (tid < 128) {
        int p = p0 + (tid & 63);
        if (p >= twoEP) p = twoEP - 1;
        int node;
        if (tid < 64) node = (p < EP) ? pos_src[p] : neg_src[p - EP];
        else          node = (p < EP) ? pos_dst[p] : neg_dst[p - EP];
        s_node[tid] = node;
    }
    __syncthreads();

    #pragma unroll
    for (int e = 0; e < 8; ++e) {
        int idx = tid + e * 256;
        int rr = idx >> 4, u = idx & 15;
        int node = s_node[rr];
        f16x8 v = *(const f16x8*)(Hf + (size_t)node * D + u * 8);
        *(f16x8*)(s_cat + (rr & 63) * LDC + (rr >> 6) * 128 + u * 8) = v;
    }
    #pragma unroll
    for (int e = 0; e < 2; ++e) {
        int idx = tid + e * 256;
        int o = idx >> 2, q = idx & 3;
        *(f16x8*)(&s_b[0][o * LDA + q * 8]) = *(const f16x8*)(P1wf + (size_t)o * 256 + q * 8);
    }
    __syncthreads();

    f32x4 acc[2][4];
    #pragma unroll
    for (int i = 0; i < 2; ++i)
        #pragma unroll
        for (int j = 0; j < 4; ++j) acc[i][j] = (f32x4){0.f, 0.f, 0.f, 0.f};

    for (int c = 0; c < 8; ++c) {
        int b = c & 1;
        f16x8 nw[2];
        if (c < 7) {
            #pragma unroll
            for (int e = 0; e < 2; ++e) {
                int idx = tid + e * 256;
                int o = idx >> 2, q = idx & 3;
                nw[e] = *(const f16x8*)(P1wf + (size_t)o * 256 + (c + 1) * 32 + q * 8);
            }
        }
        f16x8 af[2], bf[4];
        af[0] = *(const f16x8*)(s_cat + (wr * 32 + l15) * LDC + c * 32 + lk * 8);
        af[1] = *(const f16x8*)(s_cat + (wr * 32 + 16 + l15) * LDC + c * 32 + lk * 8);
        #pragma unroll
        for (int j = 0; j < 4; ++j)
            bf[j] = *(const f16x8*)(&s_b[b][(wc * 64 + j * 16 + l15) * LDA + lk * 8]);
        #pragma unroll
        for (int i = 0; i < 2; ++i)
            #pragma unroll
            for (int j = 0; j < 4; ++j)
                acc[i][j] = __builtin_amdgcn_mfma_f32_16x16x32_f16(af[i], bf[j], acc[i][j], 0, 0, 0);
        if (c < 7) {
            #pragma unroll
            for (int e = 0; e < 2; ++e) {
                int idx = tid + e * 256;
                int o = idx >> 2, q = idx & 3;
                *(f16x8*)(&s_b[b ^ 1][o * LDA + q * 8]) = nw[e];
            }
        }
        __syncthreads();
    }

    #pragma unroll
    for (int j = 0; j < 4; ++j) {
        int col = wc * 64 + j * 16 + l15;
        float bv = P1b[col];
        #pragma unroll
        for (int i = 0; i < 2; ++i) {
            int rowb = wr * 32 + i * 16 + lk * 4;
            #pragma unroll
            for (int v = 0; v < 4; ++v)
                s_cat[(rowb + v) * LDC + col] = (_Float16)fmaxf(acc[i][j][v] + bv, 0.f);
        }
    }
    #pragma unroll
    for (int e = 0; e < 2; ++e) {
        int idx = tid + e * 256;
        int o = idx >> 2, q = idx & 3;
        *(f16x8*)(&s_b[0][o * LDA + q * 8]) = *(const f16x8*)(P2wf + (size_t)o * D + q * 8);
    }
    __syncthreads();

    f32x4 acc2[2][4];
    #pragma unroll
    for (int i = 0; i < 2; ++i)
        #pragma unroll
        for (int j = 0; j < 4; ++j) acc2[i][j] = (f32x4){0.f, 0.f, 0.f, 0.f};

    for (int c = 0; c < 4; ++c) {
        int b = c & 1;
        f16x8 nw[2];
        if (c < 3) {
            #pragma unroll
            for (int e = 0; e < 2; ++e) {
                int idx = tid + e * 256;
                int o = idx >> 2, q = idx & 3;
                nw[e] = *(const f16x8*)(P2wf + (size_t)o * D + (c + 1) * 32 + q * 8);
            }
        }
        f16x8 af[2], bf[4];
        af[0] = *(const f16x8*)(s_cat + (wr * 32 + l15) * LDC + c * 32 + lk * 8);
        af[1] = *(const f16x8*)(s_cat + (wr * 32 + 16 + l15) * LDC + c * 32 + lk * 8);
        #pragma unroll
        for (int j = 0; j < 4; ++j)
            bf[j] = *(const f16x8*)(&s_b[b][(wc * 64 + j * 16 + l15) * LDA + lk * 8]);
        #pragma unroll
        for (int i = 0; i < 2; ++i)
            #pragma unroll
            for (int j = 0; j < 4; ++j)
                acc2[i][j] = __builtin_amdgcn_mfma_f32_16x16x32_f16(af[i], bf[j], acc2[i][j], 0, 0, 0);
        if (c < 3) {
            #pragma unroll
            for (int e = 0; e < 2; ++e) {
                int idx = tid + e * 256;
                int o = idx >> 2, q = idx & 3;
                *(f16x8*)(&s_b[b ^ 1][o * LDA + q * 8]) = nw[e];
            }
        }
        __syncthreads();
    }

    float b2v[4], pw[4];
    #pragma unroll
    for (int j = 0; j < 4; ++j) {
        int col = wc * 64 + j * 16 + l15;
        b2v[j] = P2b[col];
        pw[j] = P3w[col];
    }
    #pragma unroll
    for (int i = 0; i < 2; ++i) {
        #pragma unroll
        for (int v = 0; v < 4; ++v) {
            float s = 0.f;
            #pragma unroll
            for (int j = 0; j < 4; ++j)
                s += fmaxf(acc2[i][j][v] + b2v[j], 0.f) * pw[j];
            s += __shfl_xor(s, 1);
            s += __shfl_xor(s, 2);
            s += __shfl_xor(s, 4);
            s += __shfl_xor(s, 8);
            if (l15 == 0)
                s_red[(wr * 32 + i * 16 + lk * 4 + v) * 2 + wc] = s;
        }
    }
    __syncthreads();
    if (tid < 64) {
        int p = p0 + tid;
        if (p < twoEP) out[p] = s_red[tid * 2] + s_red[tid * 2 + 1] + P3b[0];
    }
}

static inline size_t align_up(size_t x, size_t a) { return (x + a - 1) & ~(a - 1); }

extern "C" void kernel_launch(void* const* d_in, const int* in_sizes, int n_in,
                              void* d_out, int out_size, void* d_ws, size_t ws_size,
                              hipStream_t stream) {
    const float* x        = (const float*)d_in[0];
    const int*   edge_src = (const int*)d_in[1];
    const int*   edge_dst = (const int*)d_in[2];
    const int*   pos_src  = (const int*)d_in[3];
    const int*   pos_dst  = (const int*)d_in[4];
    const int*   neg_src  = (const int*)d_in[5];
    const int*   neg_dst  = (const int*)d_in[6];
    const float* W1n = (const float*)d_in[7];
    const float* W1s = (const float*)d_in[8];
    const float* b1  = (const float*)d_in[9];
    const float* W2n = (const float*)d_in[10];
    const float* W2s = (const float*)d_in[11];
    const float* b2  = (const float*)d_in[12];
    const float* P1w = (const float*)d_in[13];
    const float* P1b = (const float*)d_in[14];
    const float* P2w = (const float*)d_in[15];
    const float* P2b = (const float*)d_in[16];
    const float* P3w = (const float*)d_in[17];
    const float* P3b = (const float*)d_in[18];
    float* out = (float*)d_out;

    const int N = in_sizes[0] / D;
    const int E = in_sizes[1];
    const int EP = in_sizes[3];

    char* ws = (char*)d_ws;
    size_t off = 0;
    int* row_off = (int*)(ws + off); off = align_up(off + (size_t)(N + 1) * 4, 256);
    int* cursor  = (int*)(ws + off); off = align_up(off + (size_t)N * 4, 256);
    int* bsums   = (int*)(ws + off); off = align_up(off + 4096, 256);
    int* csr     = (int*)(ws + off); off = align_up(off + (size_t)E * 4, 256);
    _Float16* xf   = (_Float16*)(ws + off); off = align_up(off + (size_t)N * D * 2, 256);
    _Float16* aggf = (_Float16*)(ws + off); off = align_up(off + (size_t)N * D * 2, 256);
    _Float16* h1f  = (_Float16*)(ws + off); off = align_up(off + (size_t)N * D * 2, 256);
    _Float16* h2f  = (_Float16*)(ws + off); off = align_up(off + (size_t)N * D * 2, 256);
    _Float16* Ws1f = (_Float16*)(ws + off); off = align_up(off + (size_t)D * D * 2, 256);
    _Float16* Wn1f = (_Float16*)(ws + off); off = align_up(off + (size_t)D * D * 2, 256);
    _Float16* Ws2f = (_Float16*)(ws + off); off = align_up(off + (size_t)D * D * 2, 256);
    _Float16* Wn2f = (_Float16*)(ws + off); off = align_up(off + (size_t)D * D * 2, 256);
    _Float16* P1wf = (_Float16*)(ws + off); off = align_up(off + (size_t)2 * D * D * 2, 256);
    _Float16* P2wf = (_Float16*)(ws + off); off = align_up(off + (size_t)D * D * 2, 256);
    (void)ws_size;

    const int nb_scan = (N + SCAN_B - 1) / SCAN_B;
    const int GR = 1024;   // 8 regions x 128 slices

    // --- CSR build (region-partitioned) ---
    hipMemsetAsync(cursor, 0, (size_t)N * 4, stream);
    k_count_deg<<<GR, 256, 0, stream>>>(edge_dst, cursor, E, N);
    k_scan_block<<<nb_scan, SCAN_B, 0, stream>>>(cursor, row_off, bsums, N);
    k_scan_sums<<<1, 64, 0, stream>>>(bsums, nb_scan);
    k_scan_add<<<nb_scan, SCAN_B, 0, stream>>>(row_off, bsums, N);
    hipMemsetAsync(cursor, 0, (size_t)N * 4, stream);
    k_scatter<<<GR, 256, 0, stream>>>(edge_src, edge_dst, row_off, cursor, csr, E, N);

    // --- f16 conversions ---
    k_cvt_f16<<<(N * D / 8 + 255) / 256, 256, 0, stream>>>(x, xf, N * D / 8);
    k_cvt_f16<<<(D * D / 8 + 255) / 256, 256, 0, stream>>>(W1s, Ws1f, D * D / 8);
    k_cvt_f16<<<(D * D / 8 + 255) / 256, 256, 0, stream>>>(W1n, Wn1f, D * D / 8);
    k_cvt_f16<<<(D * D / 8 + 255) / 256, 256, 0, stream>>>(W2s, Ws2f, D * D / 8);
    k_cvt_f16<<<(D * D / 8 + 255) / 256, 256, 0, stream>>>(W2n, Wn2f, D * D / 8);
    k_cvt_f16<<<(2 * D * D / 8 + 255) / 256, 256, 0, stream>>>(P1w, P1wf, 2 * D * D / 8);
    k_cvt_f16<<<(D * D / 8 + 255) / 256, 256, 0, stream>>>(P2w, P2wf, D * D / 8);

    const int ngrid = (N + 127) / 128;
    const int pgrid = (2 * EP + 63) / 64;

    // --- layer 1 ---
    k_agg<<<(N + 15) / 16, 256, 0, stream>>>(xf, row_off, csr, aggf, N);
    k_transform<<<ngrid, 512, 0, stream>>>(xf, aggf, Ws1f, Wn1f, b1, h1f, N, 1);
    // --- layer 2 ---
    k_agg<<<(N + 15) / 16, 256, 0, stream>>>(h1f, row_off, csr, aggf, N);
    k_transform<<<ngrid, 512, 0, stream>>>(h1f, aggf, Ws2f, Wn2f, b2, h2f, N, 0);

    // --- fused predictor ---
    k_mlp<<<pgrid, 256, 0, stream>>>(h2f, pos_src, pos_dst, neg_src, neg_dst,
                                     P1wf, P1b, P2wf, P2b, P3w, P3b, out, EP);
}